// Round 1
// baseline (55.538 us; speedup 1.0000x reference)
//
#include <hip/hip_runtime.h>

// out_p = cos(phase)*xp + sin(phase)*xq
// out_q = cos(phase)*xq - sin(phase)*xp
// where x = [p,q] - r, phase = -2*h*alpha*eps^2*exp(-eps^2*||x||^2)
// DIM = 16 -> 4 float4 per row per array.

__global__ __launch_bounds__(256) void symplectic_rot_kernel(
    const float* __restrict__ p,
    const float* __restrict__ q,
    const float* __restrict__ h,
    const float* __restrict__ r,
    const float* __restrict__ eps,
    const float* __restrict__ alpha,
    float* __restrict__ out,
    int nrows)
{
    int i = blockIdx.x * blockDim.x + threadIdx.x;
    if (i >= nrows) return;

    const float4* p4  = reinterpret_cast<const float4*>(p) + (size_t)i * 4;
    const float4* q4  = reinterpret_cast<const float4*>(q) + (size_t)i * 4;
    const float4* rp4 = reinterpret_cast<const float4*>(r);      // r[0..15]
    const float4* rq4 = reinterpret_cast<const float4*>(r) + 4;  // r[16..31]

    float4 xp[4], xq[4];
    float y = 0.0f;

    #pragma unroll
    for (int k = 0; k < 4; ++k) {
        float4 pv = p4[k];
        float4 rv = rp4[k];
        float4 x;
        x.x = pv.x - rv.x; x.y = pv.y - rv.y;
        x.z = pv.z - rv.z; x.w = pv.w - rv.w;
        xp[k] = x;
        y += x.x * x.x + x.y * x.y + x.z * x.z + x.w * x.w;
    }
    #pragma unroll
    for (int k = 0; k < 4; ++k) {
        float4 qv = q4[k];
        float4 rv = rq4[k];
        float4 x;
        x.x = qv.x - rv.x; x.y = qv.y - rv.y;
        x.z = qv.z - rv.z; x.w = qv.w - rv.w;
        xq[k] = x;
        y += x.x * x.x + x.y * x.y + x.z * x.z + x.w * x.w;
    }

    float e    = eps[0];
    float eps2 = e * e;
    float phase = -2.0f * h[0] * alpha[0] * eps2 * __expf(-eps2 * y);

    float s, c;
    __sincosf(phase, &s, &c);

    float4* op = reinterpret_cast<float4*>(out) + (size_t)i * 4;
    float4* oq = reinterpret_cast<float4*>(out) + (size_t)nrows * 4 + (size_t)i * 4;

    #pragma unroll
    for (int k = 0; k < 4; ++k) {
        float4 a = xp[k];
        float4 b = xq[k];
        float4 o1, o2;
        o1.x = c * a.x + s * b.x; o1.y = c * a.y + s * b.y;
        o1.z = c * a.z + s * b.z; o1.w = c * a.w + s * b.w;
        o2.x = c * b.x - s * a.x; o2.y = c * b.y - s * a.y;
        o2.z = c * b.z - s * a.z; o2.w = c * b.w - s * a.w;
        op[k] = o1;
        oq[k] = o2;
    }
}

extern "C" void kernel_launch(void* const* d_in, const int* in_sizes, int n_in,
                              void* d_out, int out_size, void* d_ws, size_t ws_size,
                              hipStream_t stream) {
    const float* p     = (const float*)d_in[0];
    const float* q     = (const float*)d_in[1];
    const float* h     = (const float*)d_in[2];
    const float* r     = (const float*)d_in[3];
    const float* eps   = (const float*)d_in[4];
    const float* alpha = (const float*)d_in[5];
    float* out = (float*)d_out;

    const int DIM = 16;
    int nrows = in_sizes[0] / DIM;

    int block = 256;
    int grid  = (nrows + block - 1) / block;
    symplectic_rot_kernel<<<grid, block, 0, stream>>>(p, q, h, r, eps, alpha, out, nrows);
}

// Round 2
// 43.241 us; speedup vs baseline: 1.2844x; 1.2844x over previous
//
#include <hip/hip_runtime.h>

// out_p = cos(phase)*xp + sin(phase)*xq
// out_q = cos(phase)*xq - sin(phase)*xp
// where x = [p,q] - r, phase = -2*h*alpha*eps^2*exp(-eps^2*||x||^2)
// DIM = 16. Layout: 4 threads per row, one float4 each -> perfectly
// coalesced 16B/lane loads & stores. Row reduction via 4-lane shfl_xor.

__global__ __launch_bounds__(256) void symplectic_rot_kernel(
    const float* __restrict__ p,
    const float* __restrict__ q,
    const float* __restrict__ h,
    const float* __restrict__ r,
    const float* __restrict__ eps,
    const float* __restrict__ alpha,
    float* __restrict__ out,
    int nrows)
{
    size_t t     = (size_t)blockIdx.x * blockDim.x + threadIdx.x;
    size_t total = (size_t)nrows * 4;          // 4 float4-slots per row
    if (t >= total) return;

    int k = (int)(t & 3);                      // which float4 of the row

    float4 pv = reinterpret_cast<const float4*>(p)[t];
    float4 qv = reinterpret_cast<const float4*>(q)[t];
    float4 rp = reinterpret_cast<const float4*>(r)[k];      // r[0..15]
    float4 rq = reinterpret_cast<const float4*>(r)[k + 4];  // r[16..31]

    float4 xp, xq;
    xp.x = pv.x - rp.x; xp.y = pv.y - rp.y;
    xp.z = pv.z - rp.z; xp.w = pv.w - rp.w;
    xq.x = qv.x - rq.x; xq.y = qv.y - rq.y;
    xq.z = qv.z - rq.z; xq.w = qv.w - rq.w;

    float part = xp.x * xp.x + xp.y * xp.y + xp.z * xp.z + xp.w * xp.w
               + xq.x * xq.x + xq.y * xq.y + xq.z * xq.z + xq.w * xq.w;

    // reduce squared distance across the 4 lanes of this row
    part += __shfl_xor(part, 1);
    part += __shfl_xor(part, 2);

    float e    = eps[0];
    float eps2 = e * e;
    float phase = -2.0f * h[0] * alpha[0] * eps2 * __expf(-eps2 * part);

    float s, c;
    __sincosf(phase, &s, &c);

    float4 o1, o2;
    o1.x = c * xp.x + s * xq.x; o1.y = c * xp.y + s * xq.y;
    o1.z = c * xp.z + s * xq.z; o1.w = c * xp.w + s * xq.w;
    o2.x = c * xq.x - s * xp.x; o2.y = c * xq.y - s * xp.y;
    o2.z = c * xq.z - s * xp.z; o2.w = c * xq.w - s * xp.w;

    reinterpret_cast<float4*>(out)[t]         = o1;
    reinterpret_cast<float4*>(out)[total + t] = o2;
}

extern "C" void kernel_launch(void* const* d_in, const int* in_sizes, int n_in,
                              void* d_out, int out_size, void* d_ws, size_t ws_size,
                              hipStream_t stream) {
    const float* p     = (const float*)d_in[0];
    const float* q     = (const float*)d_in[1];
    const float* h     = (const float*)d_in[2];
    const float* r     = (const float*)d_in[3];
    const float* eps   = (const float*)d_in[4];
    const float* alpha = (const float*)d_in[5];
    float* out = (float*)d_out;

    const int DIM = 16;
    int nrows = in_sizes[0] / DIM;

    long long nthreads = (long long)nrows * 4;
    int block = 256;
    long long grid = (nthreads + block - 1) / block;
    symplectic_rot_kernel<<<(int)grid, block, 0, stream>>>(p, q, h, r, eps, alpha, out, nrows);
}

// Round 4
// 43.024 us; speedup vs baseline: 1.2908x; 1.0050x over previous
//
#include <hip/hip_runtime.h>

// out_p = cos(phase)*xp + sin(phase)*xq
// out_q = cos(phase)*xq - sin(phase)*xp
// where x = [p,q] - r, phase = -2*h*alpha*eps^2*exp(-eps^2*||x||^2)
// DIM = 16. 4 threads/row, one float4 each -> perfectly coalesced.
// Row reduction via 4-lane shfl_xor. Output stores are NONTEMPORAL (via
// native ext_vector_type, which the builtin requires) so the write-only
// stream doesn't evict the reused-across-replays inputs from L3.

typedef float floatx4 __attribute__((ext_vector_type(4)));

__global__ __launch_bounds__(256) void symplectic_rot_kernel(
    const float* __restrict__ p,
    const float* __restrict__ q,
    const float* __restrict__ h,
    const float* __restrict__ r,
    const float* __restrict__ eps,
    const float* __restrict__ alpha,
    float* __restrict__ out,
    int nrows)
{
    size_t t     = (size_t)blockIdx.x * blockDim.x + threadIdx.x;
    size_t total = (size_t)nrows * 4;          // 4 float4-slots per row
    if (t >= total) return;

    int k = (int)(t & 3);                      // which float4 of the row

    floatx4 pv = reinterpret_cast<const floatx4*>(p)[t];
    floatx4 qv = reinterpret_cast<const floatx4*>(q)[t];
    floatx4 rp = reinterpret_cast<const floatx4*>(r)[k];      // r[0..15]
    floatx4 rq = reinterpret_cast<const floatx4*>(r)[k + 4];  // r[16..31]

    floatx4 xp = pv - rp;
    floatx4 xq = qv - rq;

    float part = xp.x * xp.x + xp.y * xp.y + xp.z * xp.z + xp.w * xp.w
               + xq.x * xq.x + xq.y * xq.y + xq.z * xq.z + xq.w * xq.w;

    // reduce squared distance across the 4 lanes of this row
    part += __shfl_xor(part, 1);
    part += __shfl_xor(part, 2);

    float e    = eps[0];
    float eps2 = e * e;
    float phase = -2.0f * h[0] * alpha[0] * eps2 * __expf(-eps2 * part);

    float s, c;
    __sincosf(phase, &s, &c);

    floatx4 o1 = c * xp + s * xq;
    floatx4 o2 = c * xq - s * xp;

    floatx4* op = reinterpret_cast<floatx4*>(out) + t;
    floatx4* oq = reinterpret_cast<floatx4*>(out) + total + t;
    __builtin_nontemporal_store(o1, op);
    __builtin_nontemporal_store(o2, oq);
}

extern "C" void kernel_launch(void* const* d_in, const int* in_sizes, int n_in,
                              void* d_out, int out_size, void* d_ws, size_t ws_size,
                              hipStream_t stream) {
    const float* p     = (const float*)d_in[0];
    const float* q     = (const float*)d_in[1];
    const float* h     = (const float*)d_in[2];
    const float* r     = (const float*)d_in[3];
    const float* eps   = (const float*)d_in[4];
    const float* alpha = (const float*)d_in[5];
    float* out = (float*)d_out;

    const int DIM = 16;
    int nrows = in_sizes[0] / DIM;

    long long nthreads = (long long)nrows * 4;
    int block = 256;
    long long grid = (nthreads + block - 1) / block;
    symplectic_rot_kernel<<<(int)grid, block, 0, stream>>>(p, q, h, r, eps, alpha, out, nrows);
}